// Round 1
// baseline (1871.013 us; speedup 1.0000x reference)
//
#include <hip/hip_runtime.h>
#include <stdint.h>

typedef unsigned short u16;
using short8  = __attribute__((ext_vector_type(8))) short;
using float4v = __attribute__((ext_vector_type(4))) float;

__device__ inline float4v f4zero() { float4v z = {0.f, 0.f, 0.f, 0.f}; return z; }

__device__ inline u16 f2bf(float f) {
  union { float f; uint32_t i; } v; v.f = f;
  uint32_t r = v.i + 0x7fffu + ((v.i >> 16) & 1u);
  return (u16)(r >> 16);
}

// ---------------------------------------------------------------------------
// Weight transpose+cast: fp32 (K,N) row-major -> bf16 (N,K) row-major.
// grid: (N/32, K/32, L), block: 256 (32x8)
// ---------------------------------------------------------------------------
__global__ __launch_bounds__(256) void transpose_cast_kernel(
    const float* __restrict__ in, u16* __restrict__ out, int K, int N) {
  __shared__ float tile[32][33];
  const int tx = threadIdx.x & 31, ty = threadIdx.x >> 5;
  in  += (size_t)blockIdx.z * K * N;
  out += (size_t)blockIdx.z * K * N;
  const int n  = blockIdx.x * 32 + tx;
  const int k0 = blockIdx.y * 32;
#pragma unroll
  for (int j = 0; j < 32; j += 8)
    tile[ty + j][tx] = in[(size_t)(k0 + ty + j) * N + n];
  __syncthreads();
  const int k = k0 + tx;
  const int n0 = blockIdx.x * 32;
#pragma unroll
  for (int j = 0; j < 32; j += 8)
    out[(size_t)(n0 + ty + j) * K + k] = f2bf(tile[tx][ty + j]);
}

// fp32 -> bf16 elementwise (4/thread)
__global__ __launch_bounds__(256) void cast_kernel(const float* __restrict__ in,
                                                   u16* __restrict__ out) {
  const int i = (blockIdx.x * 256 + threadIdx.x) * 4;
  float4 t = *(const float4*)(in + i);
  ushort4 o;
  o.x = f2bf(t.x); o.y = f2bf(t.y); o.z = f2bf(t.z); o.w = f2bf(t.w);
  *(ushort4*)(out + i) = o;
}

// ---------------------------------------------------------------------------
// GEMM: C[M,N] = A[M,K] (bf16, row-major) * W[K,N]  with W given as Wt (N,K) bf16.
// 128x128 tile, BK=64, 4 waves (each 64x64 = 4x4 mfma frags), mfma 16x16x32 bf16.
// EPI: 0 = Q/K scatter (B,NH,S,DH) bf16 (+bias)
//      1 = V scatter   (B,NH,DH,S) bf16 (+bias)
//      2 = fp32 out = acc + bias + resid
//      3 = bf16 out = gelu_exact(acc + bias)
// ---------------------------------------------------------------------------
template <int M, int N, int K, int EPI>
__global__ __launch_bounds__(256) void gemm_kernel(
    const u16* __restrict__ A, const u16* __restrict__ Wt,
    const float* __restrict__ bias, const float* __restrict__ resid,
    void* __restrict__ outp) {
  __shared__ __align__(16) u16 As[128][72];
  __shared__ __align__(16) u16 Bs[128][72];
  const int tid  = threadIdx.x;
  const int lane = tid & 63;
  const int wv   = tid >> 6;
  const int quad = lane >> 4, mm = lane & 15;
  const int m0 = blockIdx.x * 128, n0 = blockIdx.y * 128;
  const int wm = (wv >> 1) * 64, wn = (wv & 1) * 64;

  float4v acc[4][4];
#pragma unroll
  for (int i = 0; i < 4; i++)
#pragma unroll
    for (int j = 0; j < 4; j++) acc[i][j] = f4zero();

  for (int kt = 0; kt < K; kt += 64) {
#pragma unroll
    for (int i = 0; i < 4; i++) {
      const int c = tid + 256 * i;      // 1024 chunks of 16B
      const int row = c >> 3, kc = c & 7;
      *(uint4*)(&As[row][kc * 8]) = *(const uint4*)(A  + (size_t)(m0 + row) * K + kt + kc * 8);
      *(uint4*)(&Bs[row][kc * 8]) = *(const uint4*)(Wt + (size_t)(n0 + row) * K + kt + kc * 8);
    }
    __syncthreads();
#pragma unroll
    for (int ks = 0; ks < 2; ks++) {
      short8 a[4], b[4];
#pragma unroll
      for (int i = 0; i < 4; i++) a[i] = *(const short8*)(&As[wm + i * 16 + mm][ks * 32 + quad * 8]);
#pragma unroll
      for (int j = 0; j < 4; j++) b[j] = *(const short8*)(&Bs[wn + j * 16 + mm][ks * 32 + quad * 8]);
#pragma unroll
      for (int i = 0; i < 4; i++)
#pragma unroll
        for (int j = 0; j < 4; j++)
          acc[i][j] = __builtin_amdgcn_mfma_f32_16x16x32_bf16(a[i], b[j], acc[i][j], 0, 0, 0);
    }
    __syncthreads();
  }

#pragma unroll
  for (int i = 0; i < 4; i++) {
#pragma unroll
    for (int j = 0; j < 4; j++) {
      const int gn = n0 + wn + j * 16 + mm;
      const float bv_ = bias[gn];
#pragma unroll
      for (int r = 0; r < 4; r++) {
        const int gm = m0 + wm + i * 16 + quad * 4 + r;
        float val = acc[i][j][r] + bv_;
        if (EPI == 0) {        // Q/K -> (B,NH,S,DH)
          const int b_ = gm >> 11, s_ = gm & 2047, h_ = gn >> 6, d_ = gn & 63;
          ((u16*)outp)[((size_t)((b_ * 8 + h_) * 2048 + s_)) * 64 + d_] = f2bf(val);
        } else if (EPI == 1) { // V -> (B,NH,DH,S)
          const int b_ = gm >> 11, s_ = gm & 2047, h_ = gn >> 6, d_ = gn & 63;
          ((u16*)outp)[((size_t)((b_ * 8 + h_) * 64 + d_)) * 2048 + s_] = f2bf(val);
        } else if (EPI == 2) { // fp32 + residual
          const size_t idx = (size_t)gm * N + gn;
          ((float*)outp)[idx] = val + resid[idx];
        } else {               // exact-erf GELU -> bf16
          const float z  = val * 0.70710678118654752f;
          const float az = fabsf(z);
          const float t  = __builtin_amdgcn_rcpf(1.0f + 0.3275911f * az);
          const float poly = t * (0.254829592f + t * (-0.284496736f +
                             t * (1.421413741f + t * (-1.453152027f + t * 1.061405429f))));
          const float e = __builtin_amdgcn_exp2f(-az * az * 1.4426950408889634f);
          float erf_ = 1.0f - poly * e;
          erf_ = (z < 0.0f) ? -erf_ : erf_;
          ((u16*)outp)[(size_t)gm * N + gn] = f2bf(val * 0.5f * (1.0f + erf_));
        }
      }
    }
  }
}

// ---------------------------------------------------------------------------
// Flash attention. grid (S/64, B*NH), block 256 (4 waves, 16 q-rows each).
// Q,K: (B,NH,S,DH) bf16. V: (B,NH,DH,S) bf16. out ctx: (B,S,H) bf16.
// scores = QK^T * inv_scale + pos_bias + mask;  inv_scale = (u+60000)/(9u+480000),
// u = max(float(tq-tk), 0)   [== 1/(sqrt(64) - 1/(lag+1) + 1), lag = u/60000]
// ---------------------------------------------------------------------------
__global__ __launch_bounds__(256) void flash_kernel(
    const u16* __restrict__ Q, const u16* __restrict__ Kb, const u16* __restrict__ Vt,
    const float* __restrict__ pb, const float* __restrict__ mask,
    const int* __restrict__ ts, u16* __restrict__ ctx) {
  __shared__ __align__(16) u16 P_lds[4][16][72];
  const int tid  = threadIdx.x;
  const int lane = tid & 63, w = tid >> 6;
  const int quad = lane >> 4, mm = lane & 15;
  const int bh = blockIdx.y, b_ = bh >> 3, h_ = bh & 7;
  const int q0 = blockIdx.x * 64 + w * 16;
  const float L2E = 1.4426950408889634f;

  const size_t qk_base = (size_t)bh * 2048 * 64;
  short8 aq[2];
#pragma unroll
  for (int t = 0; t < 2; t++)
    aq[t] = *(const short8*)(Q + qk_base + (size_t)(q0 + mm) * 64 + t * 32 + quad * 8);

  int tq[4];
#pragma unroll
  for (int r = 0; r < 4; r++) tq[r] = ts[b_ * 2048 + q0 + quad * 4 + r];

  float m_r[4], l_r[4];
  float4v o[4];
#pragma unroll
  for (int r = 0; r < 4; r++) { m_r[r] = -1e30f; l_r[r] = 0.0f; }
#pragma unroll
  for (int ob = 0; ob < 4; ob++) o[ob] = f4zero();

  for (int k0 = 0; k0 < 2048; k0 += 64) {
    float4v s[4];
#pragma unroll
    for (int nb = 0; nb < 4; nb++) {
      const short8 bk0 = *(const short8*)(Kb + qk_base + (size_t)(k0 + nb * 16 + mm) * 64 + quad * 8);
      const short8 bk1 = *(const short8*)(Kb + qk_base + (size_t)(k0 + nb * 16 + mm) * 64 + 32 + quad * 8);
      s[nb] = __builtin_amdgcn_mfma_f32_16x16x32_bf16(aq[0], bk0, f4zero(), 0, 0, 0);
      s[nb] = __builtin_amdgcn_mfma_f32_16x16x32_bf16(aq[1], bk1, s[nb], 0, 0, 0);
    }
    float st[4][4];
#pragma unroll
    for (int nb = 0; nb < 4; nb++) {
      const int kcol = k0 + nb * 16 + mm;
      const int tk   = ts[b_ * 2048 + kcol];
      const float mk = mask[b_ * 2048 + kcol];
#pragma unroll
      for (int r = 0; r < 4; r++) {
        float u = (float)(tq[r] - tk);
        u = fmaxf(u, 0.0f);
        const float inv = (u + 60000.0f) * __builtin_amdgcn_rcpf(fmaf(u, 9.0f, 480000.0f));
        const float pbv = pb[((size_t)h_ * 2048 + q0 + quad * 4 + r) * 2048 + kcol];
        st[nb][r] = s[nb][r] * inv + pbv + mk;
      }
    }
#pragma unroll
    for (int r = 0; r < 4; r++) {
      float mt = fmaxf(fmaxf(st[0][r], st[1][r]), fmaxf(st[2][r], st[3][r]));
#pragma unroll
      for (int sh = 1; sh < 16; sh <<= 1) mt = fmaxf(mt, __shfl_xor(mt, sh, 64));
      const float mn = fmaxf(m_r[r], mt);
      const float alpha = __builtin_amdgcn_exp2f((m_r[r] - mn) * L2E);
      float ps = 0.0f;
#pragma unroll
      for (int nb = 0; nb < 4; nb++) {
        const float p = __builtin_amdgcn_exp2f((st[nb][r] - mn) * L2E);
        st[nb][r] = p;
        ps += p;
      }
#pragma unroll
      for (int sh = 1; sh < 16; sh <<= 1) ps += __shfl_xor(ps, sh, 64);
      l_r[r] = l_r[r] * alpha + ps;
      m_r[r] = mn;
#pragma unroll
      for (int ob = 0; ob < 4; ob++) o[ob][r] *= alpha;
#pragma unroll
      for (int nb = 0; nb < 4; nb++) P_lds[w][quad * 4 + r][nb * 16 + mm] = f2bf(st[nb][r]);
    }
    const short8 ap0 = *(const short8*)(&P_lds[w][mm][quad * 8]);
    const short8 ap1 = *(const short8*)(&P_lds[w][mm][32 + quad * 8]);
    const size_t v_base = (size_t)bh * 64 * 2048;
#pragma unroll
    for (int ob = 0; ob < 4; ob++) {
      const short8 bv0 = *(const short8*)(Vt + v_base + (size_t)(ob * 16 + mm) * 2048 + k0 + quad * 8);
      const short8 bv1 = *(const short8*)(Vt + v_base + (size_t)(ob * 16 + mm) * 2048 + k0 + 32 + quad * 8);
      o[ob] = __builtin_amdgcn_mfma_f32_16x16x32_bf16(ap0, bv0, o[ob], 0, 0, 0);
      o[ob] = __builtin_amdgcn_mfma_f32_16x16x32_bf16(ap1, bv1, o[ob], 0, 0, 0);
    }
  }
#pragma unroll
  for (int r = 0; r < 4; r++) {
    const float rl = __builtin_amdgcn_rcpf(l_r[r]);
    const int qrow = q0 + quad * 4 + r;
#pragma unroll
    for (int ob = 0; ob < 4; ob++)
      ctx[((size_t)b_ * 2048 + qrow) * 512 + h_ * 64 + ob * 16 + mm] = f2bf(o[ob][r] * rl);
  }
}

// ---------------------------------------------------------------------------
// LayerNorm over H=512: 1 wave/row, 4 rows/block. Writes fp32 and bf16 copies.
// ---------------------------------------------------------------------------
__global__ __launch_bounds__(256) void ln_kernel(
    const float* __restrict__ in, const float* __restrict__ g, const float* __restrict__ bb,
    float* __restrict__ of, u16* __restrict__ obf) {
  const int lane = threadIdx.x & 63, w = threadIdx.x >> 6;
  const int row = blockIdx.x * 4 + w;
  const float* x = in + (size_t)row * 512;
  float v[8];
  const float4 t0 = *(const float4*)(x + lane * 8);
  const float4 t1 = *(const float4*)(x + lane * 8 + 4);
  v[0] = t0.x; v[1] = t0.y; v[2] = t0.z; v[3] = t0.w;
  v[4] = t1.x; v[5] = t1.y; v[6] = t1.z; v[7] = t1.w;
  float s = 0.f;
#pragma unroll
  for (int i = 0; i < 8; i++) s += v[i];
#pragma unroll
  for (int sh = 1; sh < 64; sh <<= 1) s += __shfl_xor(s, sh, 64);
  const float mean = s * (1.0f / 512.0f);
  float sq = 0.f;
#pragma unroll
  for (int i = 0; i < 8; i++) { const float d = v[i] - mean; sq += d * d; }
#pragma unroll
  for (int sh = 1; sh < 64; sh <<= 1) sq += __shfl_xor(sq, sh, 64);
  const float rstd = rsqrtf(sq * (1.0f / 512.0f) + 1e-12f);
#pragma unroll
  for (int i = 0; i < 8; i++) {
    const int col = lane * 8 + i;
    const float y = (v[i] - mean) * rstd * g[col] + bb[col];
    of[(size_t)row * 512 + col]  = y;
    obf[(size_t)row * 512 + col] = f2bf(y);
  }
}

// ---------------------------------------------------------------------------
extern "C" void kernel_launch(void* const* d_in, const int* in_sizes, int n_in,
                              void* d_out, int out_size, void* d_ws, size_t ws_size,
                              hipStream_t stream) {
  const float* x_in = (const float*)d_in[0];
  const float* mask = (const float*)d_in[1];
  const float* pb   = (const float*)d_in[2];
  const int*   ts   = (const int*)d_in[3];
  const float* wq = (const float*)d_in[4];  const float* bq = (const float*)d_in[5];
  const float* wk = (const float*)d_in[6];  const float* bk = (const float*)d_in[7];
  const float* wvp = (const float*)d_in[8]; const float* bv = (const float*)d_in[9];
  const float* wo = (const float*)d_in[10]; const float* bo = (const float*)d_in[11];
  const float* ln1g = (const float*)d_in[12]; const float* ln1b = (const float*)d_in[13];
  const float* wi = (const float*)d_in[14]; const float* bi = (const float*)d_in[15];
  const float* wo2 = (const float*)d_in[16]; const float* bo2 = (const float*)d_in[17];
  const float* ln2g = (const float*)d_in[18]; const float* ln2b = (const float*)d_in[19];

  char* ws = (char*)d_ws;
  const size_t MB = 1024 * 1024;
  u16*   wqT  = (u16*)(ws + 0 * MB);
  u16*   wkT  = (u16*)(ws + 2 * MB);
  u16*   wvT  = (u16*)(ws + 4 * MB);
  u16*   woT  = (u16*)(ws + 6 * MB);
  u16*   wiT  = (u16*)(ws + 8 * MB);
  u16*   wo2T = (u16*)(ws + 16 * MB);
  u16*   xbf  = (u16*)(ws + 24 * MB);
  float* xf32 = (float*)(ws + 32 * MB);
  u16*   qb_  = (u16*)(ws + 48 * MB);
  u16*   kb_  = (u16*)(ws + 56 * MB);
  u16*   vb_  = (u16*)(ws + 64 * MB);
  u16*   ctx  = (u16*)(ws + 72 * MB);
  u16*   hb   = (u16*)(ws + 48 * MB);   // aliases q/k/v/ctx (dead by FFN time)
  float* tmp  = (float*)(ws + 80 * MB);
  float* attnf = (float*)(ws + 96 * MB);
  u16*   attnb = (u16*)(ws + 112 * MB);

  const dim3 blk(256);
  transpose_cast_kernel<<<dim3(16, 16, 4), blk, 0, stream>>>(wq,  wqT,  512, 512);
  transpose_cast_kernel<<<dim3(16, 16, 4), blk, 0, stream>>>(wk,  wkT,  512, 512);
  transpose_cast_kernel<<<dim3(16, 16, 4), blk, 0, stream>>>(wvp, wvT,  512, 512);
  transpose_cast_kernel<<<dim3(16, 16, 4), blk, 0, stream>>>(wo,  woT,  512, 512);
  transpose_cast_kernel<<<dim3(64, 16, 4), blk, 0, stream>>>(wi,  wiT,  512, 2048);
  transpose_cast_kernel<<<dim3(16, 64, 4), blk, 0, stream>>>(wo2, wo2T, 2048, 512);
  cast_kernel<<<4096, blk, 0, stream>>>(x_in, xbf);

  const float* xres = x_in;
  for (int l = 0; l < 4; l++) {
    gemm_kernel<8192, 512, 512, 0><<<dim3(64, 4), blk, 0, stream>>>(
        xbf, wqT + (size_t)l * 262144, bq + l * 512, nullptr, qb_);
    gemm_kernel<8192, 512, 512, 0><<<dim3(64, 4), blk, 0, stream>>>(
        xbf, wkT + (size_t)l * 262144, bk + l * 512, nullptr, kb_);
    gemm_kernel<8192, 512, 512, 1><<<dim3(64, 4), blk, 0, stream>>>(
        xbf, wvT + (size_t)l * 262144, bv + l * 512, nullptr, vb_);
    flash_kernel<<<dim3(32, 32), blk, 0, stream>>>(qb_, kb_, vb_, pb, mask, ts, ctx);
    gemm_kernel<8192, 512, 512, 2><<<dim3(64, 4), blk, 0, stream>>>(
        ctx, woT + (size_t)l * 262144, bo + l * 512, xres, tmp);
    ln_kernel<<<2048, blk, 0, stream>>>(tmp, ln1g + l * 512, ln1b + l * 512, attnf, attnb);
    gemm_kernel<8192, 2048, 512, 3><<<dim3(64, 16), blk, 0, stream>>>(
        attnb, wiT + (size_t)l * 1048576, bi + l * 2048, nullptr, hb);
    gemm_kernel<8192, 512, 2048, 2><<<dim3(64, 4), blk, 0, stream>>>(
        hb, wo2T + (size_t)l * 1048576, bo2 + l * 512, attnf, tmp);
    float* oxf = (l == 3) ? (float*)d_out : xf32;
    ln_kernel<<<2048, blk, 0, stream>>>(tmp, ln2g + l * 512, ln2b + l * 512, oxf, xbf);
    xres = xf32;
  }
  (void)in_sizes; (void)n_in; (void)out_size; (void)ws_size;
}